// Round 4
// baseline (768.199 us; speedup 1.0000x reference)
//
#include <hip/hip_runtime.h>

#define SEQ   2048
#define DK    64
#define QBLK  64
#define KVBLK 64
#define NTILE (SEQ / KVBLK)
#define PITCH 72   // bf16 elements; 144B rows, 16B-aligned

typedef __attribute__((ext_vector_type(8))) __bf16 bf16x8;
typedef __attribute__((ext_vector_type(4))) __bf16 bf16x4;
typedef __attribute__((ext_vector_type(4))) float  f32x4;
typedef __attribute__((ext_vector_type(4))) int    i32x4;

__device__ __forceinline__ float grp16_max(float v) {
  v = fmaxf(v, __shfl_xor(v, 1));
  v = fmaxf(v, __shfl_xor(v, 2));
  v = fmaxf(v, __shfl_xor(v, 4));
  v = fmaxf(v, __shfl_xor(v, 8));
  return v;
}
__device__ __forceinline__ float grp16_sum(float v) {
  v += __shfl_xor(v, 1);
  v += __shfl_xor(v, 2);
  v += __shfl_xor(v, 4);
  v += __shfl_xor(v, 8);
  return v;
}

// Barrier that drains ONLY the LDS pipe. Global loads (mask/K/V prefetch)
// stay in flight across it — unlike __syncthreads(), which emits a full
// vmcnt(0) drain and serialized every prefetch in R1-R3.
// Safe here: the loop has no global writes, so cross-wave hazards are
// LDS-only (lgkmcnt) and arrival-order (s_barrier).
__device__ __forceinline__ void block_sync_lds() {
  asm volatile("s_waitcnt lgkmcnt(0)" ::: "memory");
  __builtin_amdgcn_sched_barrier(0);
  __builtin_amdgcn_s_barrier();
  __builtin_amdgcn_sched_barrier(0);
}

struct KState {
  const float* Kp; const float* Vp; const int* Mp;
  int sk, sd, sj, g, li, w, q0;
};

// Flash attention, 4 waves x 16 q-rows, KV tiles of 64.
// K staged at permuted row: Klds[j][d] = K[pi(j)][d], pi(j) = (j&15)*4 + (j>>4),
// so score col (nt*16+li) <-> kv = li*4+nt: mask loads are int4, P writes b64,
// both in TRUE kv index space; V staged unpermuted (Vt[d][kv]).
// Pipelining: mask depth-2 ping-pong regs, K/V depth-1 regs, raw LDS barriers.
__global__ __launch_bounds__(256, 2)
void sdpa_fwd(const float* __restrict__ Q, const float* __restrict__ K,
              const float* __restrict__ V, const int* __restrict__ M,
              float* __restrict__ O)
{
  __shared__ __bf16 Klds[KVBLK][PITCH];
  __shared__ __bf16 Vt[DK][PITCH];
  __shared__ __bf16 Plds[4][16][PITCH];

  const int tid  = threadIdx.x;
  const int w    = tid >> 6;
  const int lane = tid & 63;
  const int g    = lane >> 4;
  const int li   = lane & 15;

  // XCD-aware bijective swizzle (1024 blocks % 8 == 0): each XCD gets a
  // contiguous blk range -> same-bh blocks share K/V in its private L2.
  const int bid = blockIdx.x;
  const int blk = (bid & 7) * 128 + (bid >> 3);
  const int qb  = blk & (SEQ / QBLK - 1);
  const int bh  = blk >> 5;

  const float* Qp = Q + (size_t)bh * SEQ * DK;
  const float* Kp = K + (size_t)bh * SEQ * DK;
  const float* Vp = V + (size_t)bh * SEQ * DK;
  const int*   Mp = M + (size_t)bh * SEQ * SEQ;
  float*       Op = O + (size_t)bh * SEQ * DK;

  const int q0 = qb * QBLK + w * 16;

  const int sk = tid >> 2;                      // staging row 0..63
  const int sd = (tid & 3) * 16;                // staging col base
  const int sj = ((sk & 3) << 4) | (sk >> 2);   // pi^{-1}(sk) for K

  // ---- Q fragments (1/8 and log2e folded; softmax in exp2) ----
  bf16x8 qfrag[2];
  {
    const float qs = 0.125f * 1.44269504088896340736f;
    const float* qr = Qp + (size_t)(q0 + li) * DK + g * 8;
    #pragma unroll
    for (int h2 = 0; h2 < 2; ++h2) {
      f32x4 a = *(const f32x4*)(qr + h2 * 32);
      f32x4 b = *(const f32x4*)(qr + h2 * 32 + 4);
      bf16x8 f;
      #pragma unroll
      for (int e = 0; e < 4; ++e) { f[e] = (__bf16)(a[e] * qs); f[4 + e] = (__bf16)(b[e] * qs); }
      qfrag[h2] = f;
    }
  }

  f32x4 acc[4];
  #pragma unroll
  for (int c = 0; c < 4; ++c) acc[c] = (f32x4){0.f, 0.f, 0.f, 0.f};
  float m_r[4], l_r[4];
  #pragma unroll
  for (int r = 0; r < 4; ++r) { m_r[r] = -__builtin_inff(); l_r[r] = 0.f; }

  f32x4 kA[4], vA[4];
  i32x4 mA[4], mB[4];   // mask ping-pong: depth-2 pipeline

  // ---- prologue: K/V tile 0; mask tiles 0 and 1 ----
  {
    const float* ks = Kp + (size_t)sk * DK + sd;
    const float* vs = Vp + (size_t)sk * DK + sd;
    #pragma unroll
    for (int i = 0; i < 4; ++i) { kA[i] = *(const f32x4*)(ks + 4 * i); vA[i] = *(const f32x4*)(vs + 4 * i); }
    #pragma unroll
    for (int r = 0; r < 4; ++r) {
      const size_t mrow = (size_t)(q0 + 4 * g + r) * SEQ + li * 4;
      mA[r] = *(const i32x4*)(Mp + mrow);
      mB[r] = *(const i32x4*)(Mp + mrow + KVBLK);
    }
  }

  auto body = [&](int kt, i32x4 (&mc)[4], i32x4 (&mn)[4]) {
    block_sync_lds();   // WAR: prev tile's LDS reads complete

    // ---- stage regs -> LDS ----
    {
      bf16x8 klo, khi;
      #pragma unroll
      for (int e = 0; e < 4; ++e) {
        klo[e] = (__bf16)kA[0][e]; klo[4 + e] = (__bf16)kA[1][e];
        khi[e] = (__bf16)kA[2][e]; khi[4 + e] = (__bf16)kA[3][e];
      }
      *(bf16x8*)&Klds[sj][sd]     = klo;
      *(bf16x8*)&Klds[sj][sd + 8] = khi;
      #pragma unroll
      for (int qd = 0; qd < 4; ++qd)
        #pragma unroll
        for (int e = 0; e < 4; ++e)
          Vt[sd + qd * 4 + e][sk] = (__bf16)vA[qd][e];
    }

    // consume this tile's mask; refill its buffer with tile kt+2
    i32x4 msk[4];
    #pragma unroll
    for (int r = 0; r < 4; ++r) msk[r] = mc[r];

    {
      const int tm = (kt + 2 < NTILE) ? kt + 2 : 0;   // clamped, branch-free
      #pragma unroll
      for (int r = 0; r < 4; ++r)
        mc[r] = *(const i32x4*)(Mp + (size_t)(q0 + 4 * g + r) * SEQ + tm * KVBLK + li * 4);
      const int tn = (kt + 1 < NTILE) ? kt + 1 : 0;
      const float* ks = Kp + (size_t)(tn * KVBLK + sk) * DK + sd;
      const float* vs = Vp + (size_t)(tn * KVBLK + sk) * DK + sd;
      #pragma unroll
      for (int i = 0; i < 4; ++i) { kA[i] = *(const f32x4*)(ks + 4 * i); vA[i] = *(const f32x4*)(vs + 4 * i); }
    }

    block_sync_lds();   // staged tile visible; global loads still in flight

    // ---- QK^T ----
    f32x4 st[4];
    #pragma unroll
    for (int nt = 0; nt < 4; ++nt) {
      bf16x8 b0 = *(const bf16x8*)&Klds[nt * 16 + li][g * 8];
      bf16x8 b1 = *(const bf16x8*)&Klds[nt * 16 + li][32 + g * 8];
      f32x4 s = (f32x4){0.f, 0.f, 0.f, 0.f};
      s = __builtin_amdgcn_mfma_f32_16x16x32_bf16(qfrag[0], b0, s, 0, 0, 0);
      s = __builtin_amdgcn_mfma_f32_16x16x32_bf16(qfrag[1], b1, s, 0, 0, 0);
      st[nt] = s;
    }

    // ---- mask + online softmax; st[nt][r] = kv col li*4+nt of row 4g+r ----
    #pragma unroll
    for (int r = 0; r < 4; ++r) {
      float s0 = msk[r].x ? -1e9f : st[0][r];
      float s1 = msk[r].y ? -1e9f : st[1][r];
      float s2 = msk[r].z ? -1e9f : st[2][r];
      float s3 = msk[r].w ? -1e9f : st[3][r];
      float mx    = grp16_max(fmaxf(fmaxf(s0, s1), fmaxf(s2, s3)));
      float mnew  = fmaxf(m_r[r], mx);
      float alpha = __builtin_amdgcn_exp2f(m_r[r] - mnew);
      float p0 = __builtin_amdgcn_exp2f(s0 - mnew);
      float p1 = __builtin_amdgcn_exp2f(s1 - mnew);
      float p2 = __builtin_amdgcn_exp2f(s2 - mnew);
      float p3 = __builtin_amdgcn_exp2f(s3 - mnew);
      l_r[r] = l_r[r] * alpha + grp16_sum((p0 + p1) + (p2 + p3));
      m_r[r] = mnew;
      acc[0][r] *= alpha;
      acc[1][r] *= alpha;
      acc[2][r] *= alpha;
      acc[3][r] *= alpha;
      bf16x4 pk;
      pk[0] = (__bf16)p0; pk[1] = (__bf16)p1; pk[2] = (__bf16)p2; pk[3] = (__bf16)p3;
      *(bf16x4*)&Plds[w][4 * g + r][li * 4] = pk;
    }

    // wave-private P tile: writes land before fragment reads
    asm volatile("s_waitcnt lgkmcnt(0)" ::: "memory");
    __builtin_amdgcn_sched_barrier(0);

    // ---- PV ----
    bf16x8 pa0 = *(const bf16x8*)&Plds[w][li][g * 8];
    bf16x8 pa1 = *(const bf16x8*)&Plds[w][li][32 + g * 8];
    #pragma unroll
    for (int dt = 0; dt < 4; ++dt) {
      bf16x8 v0 = *(const bf16x8*)&Vt[dt * 16 + li][g * 8];
      bf16x8 v1 = *(const bf16x8*)&Vt[dt * 16 + li][32 + g * 8];
      acc[dt] = __builtin_amdgcn_mfma_f32_16x16x32_bf16(pa0, v0, acc[dt], 0, 0, 0);
      acc[dt] = __builtin_amdgcn_mfma_f32_16x16x32_bf16(pa1, v1, acc[dt], 0, 0, 0);
    }
  };

  // manual x2 unroll keeps the mask ping-pong statically indexed (rule #20)
  for (int kt = 0; kt < NTILE; kt += 2) {
    body(kt, mA, mB);
    body(kt + 1, mB, mA);
  }

  // ---- epilogue ----
  #pragma unroll
  for (int r = 0; r < 4; ++r) {
    float inv = 1.0f / l_r[r];
    float* orow = Op + (size_t)(q0 + 4 * g + r) * DK + li;
    #pragma unroll
    for (int dt = 0; dt < 4; ++dt)
      orow[dt * 16] = acc[dt][r] * inv;
  }
}

extern "C" void kernel_launch(void* const* d_in, const int* in_sizes, int n_in,
                              void* d_out, int out_size, void* d_ws, size_t ws_size,
                              hipStream_t stream) {
  const float* Q = (const float*)d_in[0];
  const float* K = (const float*)d_in[1];
  const float* V = (const float*)d_in[2];
  const int*   M = (const int*)d_in[3];
  float*       O = (float*)d_out;

  const int nblocks = 2 * 16 * (SEQ / QBLK);  // 1024
  sdpa_fwd<<<nblocks, 256, 0, stream>>>(Q, K, V, M, O);
}